// Round 7
// baseline (425.747 us; speedup 1.0000x reference)
//
#include <hip/hip_runtime.h>
#include <math.h>

// Problem constants
#define B_  4
#define S_  1024
#define D_  1024
#define H_  16
#define DK_ 64
#define M_  (B_ * S_)
#define NBLK 512   // persistent grid: 2 blocks/CU x 256 CUs, co-resident by construction

typedef __bf16 bf16x8 __attribute__((ext_vector_type(8)));
typedef float  f32x4  __attribute__((ext_vector_type(4)));

// ---- bf16 helpers (RNE) ----------------------------------------------------
__device__ __forceinline__ unsigned short f2bf(float f) {
  unsigned u = __builtin_bit_cast(unsigned, f);
  u = (u + 0x7FFFu + ((u >> 16) & 1u)) >> 16;
  return (unsigned short)u;
}
__device__ __forceinline__ float bf2f(unsigned short h) {
  unsigned u = ((unsigned)h) << 16;
  return __builtin_bit_cast(float, u);
}

// async global->LDS, 16 B per lane; LDS dest = wave-uniform base + lane*16
__device__ __forceinline__ void gl_lds16(const void* g, void* lds) {
  __builtin_amdgcn_global_load_lds(
      (const __attribute__((address_space(1))) unsigned int*)(unsigned long long)g,
      (__attribute__((address_space(3))) unsigned int*)(unsigned int)(unsigned long long)lds,
      16, 0, 0);
}

// ---- grid barrier (cooperative-groups pattern, device-scope atomics) -------
// Counters zeroed each launch by a captured hipMemsetAsync. Co-residency of
// all NBLK blocks is guaranteed by capacity (512 blocks <= 2/CU floor), so no
// block waits on an undispatched one.
__device__ __forceinline__ void grid_barrier(unsigned* ctr) {
  __syncthreads();
  if (threadIdx.x == 0) {
    __threadfence();            // agent-scope release (writeback this XCD L2)
    atomicAdd(ctr, 1u);         // device-scope by default
    while (__hip_atomic_load(ctr, __ATOMIC_ACQUIRE,
                             __HIP_MEMORY_SCOPE_AGENT) < NBLK)
      __builtin_amdgcn_s_sleep(1);
    __threadfence();            // agent-scope acquire (invalidate stale lines)
  }
  __syncthreads();
}

// ---- bf16 MFMA GEMM tile: C[64x128] = bf16(A@B + bias), BK=64 as 2x32 ------
// Identical structure to round 6 (16 MFMA/wave/barrier, 16 K-iters).
__device__ __forceinline__ void gemm_tile(
    const unsigned short* __restrict__ A, const unsigned short* __restrict__ BT,
    const float* __restrict__ bias, unsigned short* __restrict__ C,
    int flat, unsigned char* SMEM) {
  unsigned short* As = (unsigned short*)SMEM;           // [2][64*32]   8 KB
  unsigned short* Bs = (unsigned short*)(SMEM + 8192);  // [2][128*32] 16 KB

  const int tid  = threadIdx.x;
  const int bx = flat & 7;        // N tiles: 1024/128 = 8
  const int by = flat >> 3;       // M tiles: 4096/64 = 64
  const int wv   = tid >> 6;
  const int lane = tid & 63;
  const int m0 = by * 64;
  const int n0 = bx * 128;

  const int colOff = (lane & 3) * 8;
  const size_t aOff  = (size_t)(m0 + 16 * wv + (lane >> 2)) * 1024 + colOff;
  const size_t bOff0 = (size_t)(n0 + 32 * wv + (lane >> 2)) * 1024 + colOff;
  const size_t bOff1 = bOff0 + (size_t)16 * 1024;

  const int l15  = lane & 15;
  const int quad = lane >> 4;

  f32x4 acc[4][2];
#pragma unroll
  for (int i = 0; i < 4; ++i)
#pragma unroll
    for (int j = 0; j < 2; ++j) acc[i][j] = (f32x4){0.f, 0.f, 0.f, 0.f};

#pragma unroll 1
  for (int k0 = 0; k0 < 1024; k0 += 64) {
    __syncthreads();
#pragma unroll
    for (int ks = 0; ks < 2; ++ks) {
      gl_lds16(A  + aOff  + k0 + ks * 32, As + ks * 2048 + wv * 512);
      gl_lds16(BT + bOff0 + k0 + ks * 32, Bs + ks * 4096 + wv * 1024);
      gl_lds16(BT + bOff1 + k0 + ks * 32, Bs + ks * 4096 + wv * 1024 + 512);
    }
    __syncthreads();

#pragma unroll
    for (int ks = 0; ks < 2; ++ks) {
      bf16x8 af[4], bfr[2];
#pragma unroll
      for (int mi = 0; mi < 4; ++mi)
        af[mi] =
            *(const bf16x8*)(As + ks * 2048 + (mi * 16 + l15) * 32 + quad * 8);
#pragma unroll
      for (int ni = 0; ni < 2; ++ni)
        bfr[ni] = *(const bf16x8*)(Bs + ks * 4096 +
                                   (wv * 32 + ni * 16 + l15) * 32 + quad * 8);
#pragma unroll
      for (int mi = 0; mi < 4; ++mi)
#pragma unroll
        for (int ni = 0; ni < 2; ++ni)
          acc[mi][ni] = __builtin_amdgcn_mfma_f32_16x16x32_bf16(
              af[mi], bfr[ni], acc[mi][ni], 0, 0, 0);
    }
  }

  // epilogue: C/D layout col = lane&15, row = quad*4 + r (m89/m91 verified)
#pragma unroll
  for (int ni = 0; ni < 2; ++ni) {
    const int n = n0 + wv * 32 + ni * 16 + l15;
    const float bv = bias[n];
#pragma unroll
    for (int mi = 0; mi < 4; ++mi) {
#pragma unroll
      for (int r = 0; r < 4; ++r) {
        const int m = m0 + mi * 16 + quad * 4 + r;
        C[(size_t)m * 1024 + n] = f2bf(acc[mi][ni][r] + bv);
      }
    }
  }
}

// ---------------------------------------------------------------------------
// THE persistent mega-kernel: prep -> gemm1 -> gemm2+q0 -> attn -> conv,
// separated by grid barriers (replaces 5 launches + 4 inter-kernel gaps).
// ---------------------------------------------------------------------------
__global__ __launch_bounds__(256, 2) void mega_kernel(
    const float* __restrict__ x, const int* __restrict__ mask,
    const float* __restrict__ W_G, const float* __restrict__ b_G,
    const float* __restrict__ Wq, const float* __restrict__ bq,
    const float* __restrict__ Wk, const float* __restrict__ bk,
    const float* __restrict__ cw, const float* __restrict__ cb,
    unsigned short* __restrict__ Xbf, unsigned short* __restrict__ G,
    unsigned short* __restrict__ Kbf, unsigned short* __restrict__ WGT,
    unsigned short* __restrict__ WkT, float* __restrict__ part,
    float* __restrict__ ropeT, float* __restrict__ scores,
    float* __restrict__ mS, unsigned* __restrict__ bar,
    float* __restrict__ out) {
  __shared__ __align__(16) unsigned char SMEM[24576];
  const int blk = blockIdx.x;
  const int tid = threadIdx.x;

  // ==== P0: prep (X cast / W transposes / rope table), 4224 block-units ====
  {
    float (*tle)[33] = (float(*)[33])SMEM;
    for (int u = blk; u < 4224; u += NBLK) {
      __syncthreads();
      if (u < 2048) {
        const int i = (u * 256 + tid) * 2;
        const float4 v0 = ((const float4*)x)[i];
        const float4 v1 = ((const float4*)x)[i + 1];
        ushort4 h0, h1;
        h0.x = f2bf(v0.x); h0.y = f2bf(v0.y);
        h0.z = f2bf(v0.z); h0.w = f2bf(v0.w);
        h1.x = f2bf(v1.x); h1.y = f2bf(v1.y);
        h1.z = f2bf(v1.z); h1.w = f2bf(v1.w);
        ((ushort4*)Xbf)[i] = h0;
        ((ushort4*)Xbf)[i + 1] = h1;
      } else if (u < 4096) {
        const bool isG = u < 3072;
        const float* W = isG ? W_G : Wk;
        unsigned short* WT = isG ? WGT : WkT;
        const int t = u - (isG ? 2048 : 3072);
        const int k0 = (t & 31) * 32;
        const int n0 = (t >> 5) * 32;
        const int tx = tid & 31;
        const int ty = tid >> 5;  // 0..7
#pragma unroll
        for (int r = 0; r < 32; r += 8)
          tle[ty + r][tx] = W[(size_t)(k0 + ty + r) * 1024 + n0 + tx];
        __syncthreads();
#pragma unroll
        for (int r = 0; r < 32; r += 8)
          WT[(size_t)(n0 + ty + r) * 1024 + k0 + tx] = f2bf(tle[tx][ty + r]);
      } else {
        const int idx = (u - 4096) * 256 + tid;
        const int s = idx >> 5, j = idx & 31;
        const float inv =
            (float)exp(-(double)j * (9.210340371976182736 / 32.0));
        float sn, c;
        sincosf((float)s * inv, &sn, &c);
        ropeT[(size_t)s * 64 + 2 * j] = c;
        ropeT[(size_t)s * 64 + 2 * j + 1] = sn;
      }
    }
  }
  grid_barrier(bar + 0);

  // ==== P1: G = bf16(X @ W_G + b_G), 512 tiles ====
  gemm_tile(Xbf, WGT, b_G, G, blk, SMEM);
  grid_barrier(bar + 1);

  // ==== P2: K = bf16(G @ Wk + bk), 512 tiles; blocks 0..127 also q0 ====
  gemm_tile(G, WkT, bk, Kbf, blk, SMEM);
  if (blk < 128) {
    __syncthreads();  // gemm waves done with SMEM before reuse
    float (*gs)[32] = (float(*)[32])SMEM;
    const int slab = blk >> 2;            // 0..31
    const int n = (blk & 3) * 256 + tid;  // 0..1023
    if (tid < 128) {
      const int b = tid >> 5, kk = tid & 31;
      gs[b][kk] = bf2f(G[(size_t)b * S_ * D_ + slab * 32 + kk]);
    }
    __syncthreads();
    float a0 = 0.f, a1 = 0.f, a2 = 0.f, a3 = 0.f;
#pragma unroll
    for (int kk = 0; kk < 32; ++kk) {
      const float w = Wq[(size_t)(slab * 32 + kk) * D_ + n];
      a0 = fmaf(gs[0][kk], w, a0);
      a1 = fmaf(gs[1][kk], w, a1);
      a2 = fmaf(gs[2][kk], w, a2);
      a3 = fmaf(gs[3][kk], w, a3);
    }
    part[(size_t)(slab * 4 + 0) * D_ + n] = a0;
    part[(size_t)(slab * 4 + 1) * D_ + n] = a1;
    part[(size_t)(slab * 4 + 2) * D_ + n] = a2;
    part[(size_t)(slab * 4 + 3) * D_ + n] = a3;
  }
  grid_barrier(bar + 2);

  // ==== P3: attention row-0, NO-max softmax (scores are O(1) by
  //      construction: sigma ~0.2, exp can't overflow; masked -> e=0 exactly,
  //      matching the reference's underflowed exp(-1e9-m)).
  //      Writes e=exp(score) + per-chunk sums. 2048 units, 4/block. ====
  {
    float* q0s  = (float*)SMEM;           // 64 floats
    float* wred = (float*)(SMEM + 256);   // 4 floats
    for (int u = blk; u < 2048; u += NBLK) {
      const int b = u >> 9;
      const int h = (u >> 5) & 15;
      const int chunk = u & 31;
      const int bh = b * H_ + h;
      const int sl = tid >> 3;  // 0..31
      const int j  = tid & 7;   // 16B chunk within the 64-elem row
      const int s  = chunk * 32 + sl;
      __syncthreads();
      if (tid < 64) {
        const int n = h * DK_ + tid;
        float v = bq[n];
#pragma unroll
        for (int sl2 = 0; sl2 < 32; ++sl2)
          v += part[(size_t)(sl2 * 4 + b) * D_ + n];
        q0s[tid] = v;
      }
      __syncthreads();

      const ushort4* kp =
          (const ushort4*)(Kbf + ((size_t)(b * S_ + s)) * D_ + h * DK_ + j * 8);
      const ushort4 k0v = kp[0], k1v = kp[1];
      const float4* tb = (const float4*)(ropeT + (size_t)s * 64 + j * 8);
      const float4 t0 = tb[0], t1 = tb[1];

      float dot = 0.f;
      {
        const float ka = bf2f(k0v.x), kb = bf2f(k0v.y);
        dot += q0s[j * 8 + 0] * (ka * t0.x - kb * t0.y) +
               q0s[j * 8 + 1] * (kb * t0.x + ka * t0.y);
      }
      {
        const float ka = bf2f(k0v.z), kb = bf2f(k0v.w);
        dot += q0s[j * 8 + 2] * (ka * t0.z - kb * t0.w) +
               q0s[j * 8 + 3] * (kb * t0.z + ka * t0.w);
      }
      {
        const float ka = bf2f(k1v.x), kb = bf2f(k1v.y);
        dot += q0s[j * 8 + 4] * (ka * t1.x - kb * t1.y) +
               q0s[j * 8 + 5] * (kb * t1.x + ka * t1.y);
      }
      {
        const float ka = bf2f(k1v.z), kb = bf2f(k1v.w);
        dot += q0s[j * 8 + 6] * (ka * t1.z - kb * t1.w) +
               q0s[j * 8 + 7] * (kb * t1.z + ka * t1.w);
      }
      dot += __shfl_xor(dot, 1);
      dot += __shfl_xor(dot, 2);
      dot += __shfl_xor(dot, 4);
      dot *= 0.125f;  // 1/sqrt(64)
      const float e = (mask[b * S_ + s] == 0) ? 0.f : expf(dot);
      if (j == 0) scores[(size_t)bh * S_ + s] = e;

      float esum = (j == 0) ? e : 0.f;
#pragma unroll
      for (int off = 1; off < 64; off <<= 1) esum += __shfl_xor(esum, off);
      if ((tid & 63) == 0) wred[tid >> 6] = esum;
      __syncthreads();
      if (tid == 0)
        mS[(size_t)bh * 32 + chunk] = wred[0] + wred[1] + wred[2] + wred[3];
    }
  }
  grid_barrier(bar + 3);

  // ==== P4: conv1d(16->1024, k=3) + bias + ReLU over p = e * (1/sum).
  //      1024 units, 2/block. No exp in this phase at all. ====
  {
    float* ish = (float*)SMEM;                       // 16 floats
    float (*sm)[18] = (float(*)[18])(SMEM + 64);     // 16x18
    for (int u = blk; u < 1024; u += NBLK) {
      const int xT = u & 63;
      const int b  = (u >> 6) & 3;
      const int oq = u >> 8;  // 0..3
      const int s0 = xT * 16;
      const int oz = oq * 256;
      __syncthreads();
      if (tid < 16) {
        const int bh = b * H_ + tid;
        float Ssum = 0.f;
#pragma unroll
        for (int c = 0; c < 32; ++c) Ssum += mS[(size_t)bh * 32 + c];
        ish[tid] = 1.f / Ssum;
      }
      __syncthreads();
      for (int i = tid; i < 16 * 18; i += 256) {
        const int c = i / 18, ss = i % 18;
        const int gs = s0 - 1 + ss;
        sm[c][ss] = (gs >= 0 && gs < S_)
                        ? scores[(size_t)(b * H_ + c) * S_ + gs] * ish[c]
                        : 0.f;
      }
      __syncthreads();

      const int og = tid >> 4;  // 0..15
      const int si = tid & 15;  // 0..15
      float r[16][3];
#pragma unroll
      for (int c = 0; c < 16; ++c) {
        r[c][0] = sm[c][si + 0];
        r[c][1] = sm[c][si + 1];
        r[c][2] = sm[c][si + 2];
      }
#pragma unroll 1
      for (int i = 0; i < 16; ++i) {
        const int o = oz + i * 16 + og;
        const float4* wo = (const float4*)(cw + (size_t)o * 48);
        float accv = cb[o];
#pragma unroll
        for (int q = 0; q < 12; ++q) {
          const float4 w4 = wo[q];
          const int f0 = q * 4;
          accv = fmaf(r[(f0 + 0) / 3][(f0 + 0) % 3], w4.x, accv);
          accv = fmaf(r[(f0 + 1) / 3][(f0 + 1) % 3], w4.y, accv);
          accv = fmaf(r[(f0 + 2) / 3][(f0 + 2) % 3], w4.z, accv);
          accv = fmaf(r[(f0 + 3) / 3][(f0 + 3) % 3], w4.w, accv);
        }
        out[((size_t)b * D_ + o) * S_ + s0 + si] = fmaxf(accv, 0.f);
      }
    }
  }
}

// ---------------------------------------------------------------------------
// Workspace:
//  [ 0, 8M) Xbf | [8,16M) G | [16,24M) Kbf | [24,26M) WGT | [26,28M) WkT
//  [28M,+512K) part | +256K ropeT | +256K scores | +8K mS
//  [30M, +64B) barrier counters (zeroed each launch via captured memset)
// ---------------------------------------------------------------------------
extern "C" void kernel_launch(void* const* d_in, const int* in_sizes, int n_in,
                              void* d_out, int out_size, void* d_ws,
                              size_t ws_size, hipStream_t stream) {
  const float* x    = (const float*)d_in[0];
  const int*   mask = (const int*)d_in[1];
  const float* W_G  = (const float*)d_in[2];
  const float* b_G  = (const float*)d_in[3];
  const float* Wq   = (const float*)d_in[4];
  const float* bq   = (const float*)d_in[5];
  const float* Wk   = (const float*)d_in[6];
  const float* bk   = (const float*)d_in[7];
  const float* cw   = (const float*)d_in[8];
  const float* cb   = (const float*)d_in[9];
  float* out = (float*)d_out;

  char* ws = (char*)d_ws;
  unsigned short* Xbf = (unsigned short*)(ws);
  unsigned short* G   = (unsigned short*)(ws + (8u << 20));
  unsigned short* Kbf = (unsigned short*)(ws + (16u << 20));
  unsigned short* WGT = (unsigned short*)(ws + (24u << 20));
  unsigned short* WkT = (unsigned short*)(ws + (26u << 20));
  float* part   = (float*)(ws + (28u << 20));
  float* ropeT  = (float*)(ws + (28u << 20) + (512u << 10));
  float* scores = (float*)(ws + (28u << 20) + (768u << 10));
  float* mS     = (float*)(ws + (28u << 20) + (1024u << 10));
  unsigned* bar = (unsigned*)(ws + (30u << 20));

  hipMemsetAsync(bar, 0, 64, stream);  // barrier counters (capturable node)
  mega_kernel<<<NBLK, 256, 0, stream>>>(x, mask, W_G, b_G, Wq, bq, Wk, bk, cw,
                                        cb, Xbf, G, Kbf, WGT, WkT, part, ropeT,
                                        scores, mS, bar, out);
}

// Round 9
// 274.667 us; speedup vs baseline: 1.5500x; 1.5500x over previous
//
#include <hip/hip_runtime.h>
#include <math.h>

// Problem constants
#define B_  4
#define S_  1024
#define D_  1024
#define H_  16
#define DK_ 64
#define M_  (B_ * S_)   // 4096 rows for the big GEMMs

typedef __bf16 bf16x8 __attribute__((ext_vector_type(8)));
typedef float  f32x4  __attribute__((ext_vector_type(4)));

// ---- bf16 helpers (RNE) ----------------------------------------------------
__device__ __forceinline__ unsigned short f2bf(float f) {
  unsigned u = __builtin_bit_cast(unsigned, f);
  u = (u + 0x7FFFu + ((u >> 16) & 1u)) >> 16;
  return (unsigned short)u;
}
__device__ __forceinline__ float bf2f(unsigned short h) {
  unsigned u = ((unsigned)h) << 16;
  return __builtin_bit_cast(float, u);
}

// async global->LDS, 16 B per lane; LDS dest = wave-uniform base + lane*16
__device__ __forceinline__ void gl_lds16(const void* g, void* lds) {
  __builtin_amdgcn_global_load_lds(
      (const __attribute__((address_space(1))) unsigned int*)(unsigned long long)g,
      (__attribute__((address_space(3))) unsigned int*)(unsigned int)(unsigned long long)lds,
      16, 0, 0);
}

// ---------------------------------------------------------------------------
// PREP:
//  blocks [0,2048):    X fp32 -> bf16 cast (8 elems/thread)
//  blocks [2048,3072): W_G transpose+cast -> WGT bf16 [n][k]
//  blocks [3072,4096): Wk  transpose+cast -> WkT bf16 [n][k]
//  blocks [4096,4224): RoPE table tab[s*64+2j]=cos(s*inv_j), +1 = sin
//  blocks [4224,4288): gr0[b][n] = x[b,0,:]@W_G + b_G  (fp32 GEMV, 64 units:
//                      unit=(b, 64-wide n-tile); 256 thr = 64 n x 4 k-quarters)
// ---------------------------------------------------------------------------
__global__ __launch_bounds__(256) void prep_kernel(
    const float* __restrict__ X, const float* __restrict__ W_G,
    const float* __restrict__ Wk, const float* __restrict__ b_G,
    unsigned short* __restrict__ Xbf, unsigned short* __restrict__ WGT,
    unsigned short* __restrict__ WkT, float* __restrict__ tab,
    float* __restrict__ gr0) {
  __shared__ float tle[32][33];
  __shared__ float xs[1024];
  __shared__ float pall[256];
  const int blk = blockIdx.x;
  const int tid = threadIdx.x;

  if (blk < 2048) {
    const int i = (blk * 256 + tid) * 2;  // float4 index
    const float4 v0 = ((const float4*)X)[i];
    const float4 v1 = ((const float4*)X)[i + 1];
    ushort4 h0, h1;
    h0.x = f2bf(v0.x); h0.y = f2bf(v0.y); h0.z = f2bf(v0.z); h0.w = f2bf(v0.w);
    h1.x = f2bf(v1.x); h1.y = f2bf(v1.y); h1.z = f2bf(v1.z); h1.w = f2bf(v1.w);
    ((ushort4*)Xbf)[i] = h0;
    ((ushort4*)Xbf)[i + 1] = h1;
  } else if (blk < 4096) {
    const bool isG = blk < 3072;
    const float* W = isG ? W_G : Wk;
    unsigned short* WT = isG ? WGT : WkT;
    const int t = isG ? blk - 2048 : blk - 3072;
    const int k0 = (t & 31) * 32;
    const int n0 = (t >> 5) * 32;
    const int tx = tid & 31;
    const int ty = tid >> 5;  // 0..7
#pragma unroll
    for (int r = 0; r < 32; r += 8)
      tle[ty + r][tx] = W[(size_t)(k0 + ty + r) * 1024 + n0 + tx];
    __syncthreads();
#pragma unroll
    for (int r = 0; r < 32; r += 8)
      WT[(size_t)(n0 + ty + r) * 1024 + k0 + tx] = f2bf(tle[tx][ty + r]);
  } else if (blk < 4224) {
    const int idx = (blk - 4096) * 256 + tid;
    const int s = idx >> 5, j = idx & 31;
    const float inv = (float)exp(-(double)j * (9.210340371976182736 / 32.0));
    float sn, c;
    sincosf((float)s * inv, &sn, &c);
    tab[(size_t)s * 64 + 2 * j] = c;
    tab[(size_t)s * 64 + 2 * j + 1] = sn;
  } else {
    // gr0 GEMV unit
    const int u = blk - 4224;           // 0..63
    const int b = u >> 4;               // 0..3
    const int n0g = (u & 15) * 64;
    const int nl = tid & 63;
    const int kq = tid >> 6;            // 0..3
    for (int i = tid; i < 1024; i += 256) xs[i] = X[(size_t)b * S_ * D_ + i];
    __syncthreads();
    float acc = 0.f;
    const int ks = kq * 256;
    for (int k = ks; k < ks + 256; ++k)
      acc = fmaf(xs[k], W_G[(size_t)k * 1024 + n0g + nl], acc);
    pall[tid] = acc;
    __syncthreads();
    if (tid < 64)
      gr0[(size_t)b * 1024 + n0g + tid] = pall[tid] + pall[64 + tid] +
                                          pall[128 + tid] + pall[192 + tid] +
                                          b_G[n0g + tid];
  }
}

// ---------------------------------------------------------------------------
// bf16 MFMA GEMM (round-6 proven inner loop: 64x128 tile, BK=64 as 2x32,
// 16 MFMA/wave/barrier, 24 KB LDS, grid 512 = 2/CU).
// mode 1 (GEMM1): C = bf16(A@B+bias) stored; blocks >= 512 run the q0 GEMV
//                 (q0 = gr0@Wq + bq, 16 units) and unit 0 zeroes mS.
// mode 0 (GEMM2): no C store. Epilogue computes row-0 attention scores
//                 directly from the fp32 accumulators:
//                 e(b,h,s) = exp( (q0[b,h,:]..RoPE(K[b,s,h,:]))/8 ), written to
//                 scores[bh][s]; per-(block,head) sums atomicAdd'ed into mS[bh].
//                 RoPE pair partner = __shfl_xor(lane,1) (C-layout col=lane&15);
//                 dk-dot = butterfly over the 16 l15 lanes + cross-wave LDS.
//                 No-max softmax (scores O(0.3), validated round 7).
// ---------------------------------------------------------------------------
#define GM 64
#define GN 128

__global__ __launch_bounds__(256) void gemm_bf16(
    const unsigned short* __restrict__ A, const unsigned short* __restrict__ BT,
    const float* __restrict__ bias, unsigned short* __restrict__ C,
    const float* __restrict__ gr0, const float* __restrict__ Wq,
    const float* __restrict__ bq, float* __restrict__ q0,
    const float* __restrict__ tab, const int* __restrict__ mask,
    float* __restrict__ scores, float* __restrict__ mS, int mode) {
  __shared__ __align__(16) unsigned short As[2][GM * 32];   // 8 KB
  __shared__ __align__(16) unsigned short Bs[2][GN * 32];   // 16 KB
  __shared__ float schalf[4 * GM];                          // 1 KB

  const int flat = blockIdx.x;
  const int tid  = threadIdx.x;

  if (flat >= 512) {
    // ---- q0 GEMV unit (mode 1 only): q0[b][n] = gr0[b,:]@Wq[:,n] + bq[n]
    float* gs   = (float*)As;   // 4096 floats = 16 KB (fits in As+Bs? As=8KB)
    float* pall = (float*)Bs;   // reuse Bs: 1024 floats needed
    // gs needs 16 KB: As(8KB) is too small alone -> span As then first 8KB of Bs
    // (they are separate arrays; use Bs upper half for pall instead)
    float* gs2   = (float*)Bs;              // second half of gs in Bs[0..4095]
    float* pall2 = ((float*)Bs) + 2048;     // Bs floats 2048.. (8 KB in)
    const int u = flat - 512;               // 0..15
    const int n0q = u * 64;
    const int nl = tid & 63;
    const int kq = tid >> 6;
    if (u == 0 && tid < 64) mS[tid] = 0.f;  // zero softmax sums before GEMM2
    for (int i = tid; i < 2048; i += 256) gs[i] = gr0[i];        // b=0,1
    for (int i = tid; i < 2048; i += 256) gs2[i] = gr0[2048 + i];// b=2,3
    __syncthreads();
    const int ks = kq * 256;
    float a0 = 0.f, a1 = 0.f, a2 = 0.f, a3 = 0.f;
    for (int k = ks; k < ks + 256; ++k) {
      const float w = Wq[(size_t)k * 1024 + n0q + nl];
      a0 = fmaf(gs[k], w, a0);
      a1 = fmaf(gs[1024 + k], w, a1);
      a2 = fmaf(gs2[k], w, a2);
      a3 = fmaf(gs2[1024 + k], w, a3);
    }
    __syncthreads();  // gs reads done before pall overlays Bs
    pall2[tid] = a0;
    pall2[256 + tid] = a1;
    schalf[tid % 256 < 256 ? 0 : 0] = schalf[0];  // no-op keep schalf live
    float* pallA = pall2;          // [kq*64+nl] for b0, +256 b1
    float* pallB = ((float*)As);   // reuse As for b2/b3 partials
    pallB[tid] = a2;
    pallB[256 + tid] = a3;
    __syncthreads();
    if (tid < 64) {
      const float bqv = bq[n0q + tid];
      q0[(size_t)0 * 1024 + n0q + tid] = pallA[tid] + pallA[64 + tid] +
                                         pallA[128 + tid] + pallA[192 + tid] + bqv;
      q0[(size_t)1 * 1024 + n0q + tid] = pallA[256 + tid] + pallA[320 + tid] +
                                         pallA[384 + tid] + pallA[448 + tid] + bqv;
      q0[(size_t)2 * 1024 + n0q + tid] = pallB[tid] + pallB[64 + tid] +
                                         pallB[128 + tid] + pallB[192 + tid] + bqv;
      q0[(size_t)3 * 1024 + n0q + tid] = pallB[256 + tid] + pallB[320 + tid] +
                                         pallB[384 + tid] + pallB[448 + tid] + bqv;
    }
    return;
  }

  // ---- GEMM path (round-6 proven) ----
  const int bx = flat & 7;        // N tiles: 1024/128 = 8
  const int by = flat >> 3;       // M tiles: 4096/64 = 64
  const int wv   = tid >> 6;
  const int lane = tid & 63;
  const int m0 = by * GM;
  const int n0 = bx * GN;

  const int colOff = (lane & 3) * 8;
  const size_t aOff  = (size_t)(m0 + 16 * wv + (lane >> 2)) * 1024 + colOff;
  const size_t bOff0 = (size_t)(n0 + 32 * wv + (lane >> 2)) * 1024 + colOff;
  const size_t bOff1 = bOff0 + (size_t)16 * 1024;

  const int l15  = lane & 15;
  const int quad = lane >> 4;

  f32x4 acc[4][2];
#pragma unroll
  for (int i = 0; i < 4; ++i)
#pragma unroll
    for (int j = 0; j < 2; ++j) acc[i][j] = (f32x4){0.f, 0.f, 0.f, 0.f};

#pragma unroll 1
  for (int k0 = 0; k0 < 1024; k0 += 64) {
    __syncthreads();
#pragma unroll
    for (int ks = 0; ks < 2; ++ks) {
      gl_lds16(A  + aOff  + k0 + ks * 32, &As[ks][wv * 512]);
      gl_lds16(BT + bOff0 + k0 + ks * 32, &Bs[ks][wv * 1024]);
      gl_lds16(BT + bOff1 + k0 + ks * 32, &Bs[ks][wv * 1024 + 512]);
    }
    __syncthreads();

#pragma unroll
    for (int ks = 0; ks < 2; ++ks) {
      bf16x8 af[4], bfr[2];
#pragma unroll
      for (int mi = 0; mi < 4; ++mi)
        af[mi] = *(const bf16x8*)(&As[ks][(mi * 16 + l15) * 32 + quad * 8]);
#pragma unroll
      for (int ni = 0; ni < 2; ++ni)
        bfr[ni] =
            *(const bf16x8*)(&Bs[ks][(wv * 32 + ni * 16 + l15) * 32 + quad * 8]);
#pragma unroll
      for (int mi = 0; mi < 4; ++mi)
#pragma unroll
        for (int ni = 0; ni < 2; ++ni)
          acc[mi][ni] = __builtin_amdgcn_mfma_f32_16x16x32_bf16(
              af[mi], bfr[ni], acc[mi][ni], 0, 0, 0);
    }
  }

  if (mode == 1) {
    // epilogue: C/D layout col = lane&15, row = quad*4 + r (m89/m91 verified)
#pragma unroll
    for (int ni = 0; ni < 2; ++ni) {
      const int n = n0 + wv * 32 + ni * 16 + l15;
      const float bv = bias[n];
#pragma unroll
      for (int mi = 0; mi < 4; ++mi) {
#pragma unroll
        for (int r = 0; r < 4; ++r) {
          const int m = m0 + mi * 16 + quad * 4 + r;
          C[(size_t)m * 1024 + n] = f2bf(acc[mi][ni][r] + bv);
        }
      }
    }
    return;
  }

  // ---- mode 0: score epilogue. b uniform per block; wave's head uniform. ----
  const int b = m0 >> 10;          // by>>4
  const int s0 = m0 & 1023;
  const int nA = n0 + wv * 32 + l15;        // ni=0 column
  const int nB = nA + 16;                   // ni=1 column
  const float bkA = bias[nA], bkB = bias[nB];
  const float qA = q0[(size_t)b * 1024 + nA];
  const float qB = q0[(size_t)b * 1024 + nB];
  const int dkA = nA & 63, dkB = nB & 63;   // same parity (differ by 16)
  const int odd = dkA & 1;                  // lane parity
  const int baseA = dkA & ~1, baseB = dkB & ~1;

  float pm[16];
#pragma unroll
  for (int mi = 0; mi < 4; ++mi) {
#pragma unroll
    for (int r = 0; r < 4; ++r) {
      const int s = s0 + mi * 16 + quad * 4 + r;
      const float vA = acc[mi][0][r] + bkA;
      const float vB = acc[mi][1][r] + bkB;
      const float pA = __shfl_xor(vA, 1);   // K at n^1 (pair partner)
      const float pB = __shfl_xor(vB, 1);
      const float2 tA = *(const float2*)&tab[(size_t)s * 64 + baseA];
      const float2 tB = *(const float2*)&tab[(size_t)s * 64 + baseB];
      const float kwA = odd ? (vA * tA.x + pA * tA.y) : (vA * tA.x - pA * tA.y);
      const float kwB = odd ? (vB * tB.x + pB * tB.y) : (vB * tB.x - pB * tB.y);
      pm[mi * 4 + r] = kwA * qA + kwB * qB;
    }
  }
  // reduce over the 16 l15 lanes (bits 0..3 of lane)
#pragma unroll
  for (int i = 0; i < 16; ++i) {
    pm[i] += __shfl_xor(pm[i], 1);
    pm[i] += __shfl_xor(pm[i], 2);
    pm[i] += __shfl_xor(pm[i], 4);
    pm[i] += __shfl_xor(pm[i], 8);
  }
  __syncthreads();  // K-loop LDS reads long done; reuse schalf
  if (l15 == 0) {
#pragma unroll
    for (int mi = 0; mi < 4; ++mi)
#pragma unroll
      for (int r = 0; r < 4; ++r)
        schalf[wv * GM + mi * 16 + quad * 4 + r] = pm[mi * 4 + r];
  }
  __syncthreads();
  if (tid < 128) {
    const int ml = tid & 63;
    const int hsel = tid >> 6;              // 0..1
    const int head = 2 * bx + hsel;
    const int bh = b * H_ + head;
    const int s = s0 + ml;
    const float dot =
        (schalf[(hsel * 2) * GM + ml] + schalf[(hsel * 2 + 1) * GM + ml]) *
        0.125f;
    const float e = (mask[b * S_ + s] == 0) ? 0.f : expf(dot);
    scores[(size_t)bh * S_ + s] = e;
    float esum = e;
#pragma unroll
    for (int off = 1; off < 64; off <<= 1) esum += __shfl_xor(esum, off);
    if (ml == 0) atomicAdd(&mS[bh], esum);
  }
}

// ---------------------------------------------------------------------------
// Conv1d (NCH, I=16, O=1024, k=3, pad=1) + bias + ReLU over p = e / sum.
// scores hold raw e-values; mS holds per-bh sums. grid (S/16, B, 4).
// ---------------------------------------------------------------------------
__global__ __launch_bounds__(256) void conv_norm_relu_kernel(
    const float* __restrict__ scores, const float* __restrict__ mS,
    const float* __restrict__ cw, const float* __restrict__ cb,
    float* __restrict__ out) {
  const int b = blockIdx.y;
  const int s0 = blockIdx.x * 16;
  const int oz = blockIdx.z * 256;
  const int tid = threadIdx.x;

  __shared__ float ish[16];
  __shared__ float sm[16][18];  // normalized p, [c][s0-1 .. s0+16]

  if (tid < 16) ish[tid] = 1.f / mS[b * H_ + tid];
  __syncthreads();

  for (int i = tid; i < 16 * 18; i += 256) {
    const int c = i / 18, ss = i % 18;
    const int gs = s0 - 1 + ss;
    sm[c][ss] = (gs >= 0 && gs < S_)
                    ? scores[(size_t)(b * H_ + c) * S_ + gs] * ish[c]
                    : 0.f;
  }
  __syncthreads();

  const int og = tid >> 4;  // 0..15
  const int si = tid & 15;  // 0..15

  float r[16][3];
#pragma unroll
  for (int c = 0; c < 16; ++c) {
    r[c][0] = sm[c][si + 0];
    r[c][1] = sm[c][si + 1];
    r[c][2] = sm[c][si + 2];
  }

#pragma unroll 1
  for (int i = 0; i < 16; ++i) {
    const int o = oz + i * 16 + og;
    const float4* wo = (const float4*)(cw + (size_t)o * 48);
    float accv = cb[o];
#pragma unroll
    for (int q = 0; q < 12; ++q) {
      const float4 w4 = wo[q];
      const int f0 = q * 4;
      accv = fmaf(r[(f0 + 0) / 3][(f0 + 0) % 3], w4.x, accv);
      accv = fmaf(r[(f0 + 1) / 3][(f0 + 1) % 3], w4.y, accv);
      accv = fmaf(r[(f0 + 2) / 3][(f0 + 2) % 3], w4.z, accv);
      accv = fmaf(r[(f0 + 3) / 3][(f0 + 3) % 3], w4.w, accv);
    }
    out[((size_t)b * D_ + o) * S_ + s0 + si] = fmaxf(accv, 0.f);
  }
}

// ---------------------------------------------------------------------------
// Workspace (peak ~21 MB):
//  [ 0, 8M) Xbf | [8,16M) G | [16,18M) WGT | [18,20M) WkT
//  [20M,+16K) gr0 | +16K q0 | +256K ropeT | +256K scores | +256B mS
// ---------------------------------------------------------------------------
extern "C" void kernel_launch(void* const* d_in, const int* in_sizes, int n_in,
                              void* d_out, int out_size, void* d_ws,
                              size_t ws_size, hipStream_t stream) {
  const float* x    = (const float*)d_in[0];
  const int*   mask = (const int*)d_in[1];
  const float* W_G  = (const float*)d_in[2];
  const float* b_G  = (const float*)d_in[3];
  const float* Wq   = (const float*)d_in[4];
  const float* bq   = (const float*)d_in[5];
  const float* Wk   = (const float*)d_in[6];
  const float* bk   = (const float*)d_in[7];
  const float* cw   = (const float*)d_in[8];
  const float* cb   = (const float*)d_in[9];
  float* out = (float*)d_out;

  char* ws = (char*)d_ws;
  unsigned short* Xbf = (unsigned short*)(ws);
  unsigned short* G   = (unsigned short*)(ws + (8u << 20));
  unsigned short* WGT = (unsigned short*)(ws + (16u << 20));
  unsigned short* WkT = (unsigned short*)(ws + (18u << 20));
  float* gr0    = (float*)(ws + (20u << 20));
  float* q0     = (float*)(ws + (20u << 20) + (16u << 10));
  float* ropeT  = (float*)(ws + (20u << 20) + (32u << 10));
  float* scores = (float*)(ws + (20u << 20) + (288u << 10));
  float* mS     = (float*)(ws + (20u << 20) + (544u << 10));

  prep_kernel<<<4288, 256, 0, stream>>>(x, W_G, Wk, b_G, Xbf, WGT, WkT, ropeT,
                                        gr0);
  gemm_bf16<<<528, 256, 0, stream>>>(Xbf, WGT, b_G, G, gr0, Wq, bq, q0, ropeT,
                                     mask, scores, mS, 1);
  gemm_bf16<<<512, 256, 0, stream>>>(G, WkT, bk, nullptr, gr0, Wq, bq, q0,
                                     ropeT, mask, scores, mS, 0);
  conv_norm_relu_kernel<<<dim3(S_ / 16, B_, 4), 256, 0, stream>>>(
      scores, mS, cw, cb, out);
}

// Round 10
// 160.445 us; speedup vs baseline: 2.6535x; 1.7119x over previous
//
#include <hip/hip_runtime.h>
#include <math.h>

// Problem constants
#define B_  4
#define S_  1024
#define D_  1024
#define H_  16
#define DK_ 64
#define M_  (B_ * S_)   // 4096 rows for the big GEMMs

typedef __bf16 bf16x8 __attribute__((ext_vector_type(8)));
typedef float  f32x4  __attribute__((ext_vector_type(4)));

// ---- bf16 helpers (RNE) ----------------------------------------------------
__device__ __forceinline__ unsigned short f2bf(float f) {
  unsigned u = __builtin_bit_cast(unsigned, f);
  u = (u + 0x7FFFu + ((u >> 16) & 1u)) >> 16;
  return (unsigned short)u;
}
__device__ __forceinline__ float bf2f(unsigned short h) {
  unsigned u = ((unsigned)h) << 16;
  return __builtin_bit_cast(float, u);
}

// async global->LDS, 16 B per lane; LDS dest = wave-uniform base + lane*16
__device__ __forceinline__ void gl_lds16(const void* g, void* lds) {
  __builtin_amdgcn_global_load_lds(
      (const __attribute__((address_space(1))) unsigned int*)(unsigned long long)g,
      (__attribute__((address_space(3))) unsigned int*)(unsigned int)(unsigned long long)lds,
      16, 0, 0);
}

// ---------------------------------------------------------------------------
// PREP (round-6 verbatim):
//  blocks [0,2048):    X fp32 -> bf16 cast (8 elems/thread)
//  blocks [2048,3072): W_G transpose+cast -> WGT bf16 [n][k]
//  blocks [3072,4096): Wk  transpose+cast -> WkT bf16 [n][k]
//  blocks [4096,4224): RoPE table tab[s*64+2j]=cos(s*inv_j), +1 = sin
// ---------------------------------------------------------------------------
__global__ __launch_bounds__(256) void prep_kernel(
    const float* __restrict__ X, const float* __restrict__ W_G,
    const float* __restrict__ Wk, unsigned short* __restrict__ Xbf,
    unsigned short* __restrict__ WGT, unsigned short* __restrict__ WkT,
    float* __restrict__ tab) {
  __shared__ float tle[32][33];
  const int blk = blockIdx.x;
  const int tid = threadIdx.x;

  if (blk < 2048) {
    const int i = (blk * 256 + tid) * 2;  // float4 index
    const float4 v0 = ((const float4*)X)[i];
    const float4 v1 = ((const float4*)X)[i + 1];
    ushort4 h0, h1;
    h0.x = f2bf(v0.x); h0.y = f2bf(v0.y); h0.z = f2bf(v0.z); h0.w = f2bf(v0.w);
    h1.x = f2bf(v1.x); h1.y = f2bf(v1.y); h1.z = f2bf(v1.z); h1.w = f2bf(v1.w);
    ((ushort4*)Xbf)[i] = h0;
    ((ushort4*)Xbf)[i + 1] = h1;
  } else if (blk < 4096) {
    const bool isG = blk < 3072;
    const float* W = isG ? W_G : Wk;
    unsigned short* WT = isG ? WGT : WkT;
    const int t = isG ? blk - 2048 : blk - 3072;
    const int k0 = (t & 31) * 32;
    const int n0 = (t >> 5) * 32;
    const int tx = tid & 31;
    const int ty = tid >> 5;  // 0..7
#pragma unroll
    for (int r = 0; r < 32; r += 8)
      tle[ty + r][tx] = W[(size_t)(k0 + ty + r) * 1024 + n0 + tx];
    __syncthreads();
#pragma unroll
    for (int r = 0; r < 32; r += 8)
      WT[(size_t)(n0 + ty + r) * 1024 + k0 + tx] = f2bf(tle[tx][ty + r]);
  } else {
    const int idx = (blk - 4096) * 256 + tid;
    const int s = idx >> 5, j = idx & 31;
    const float inv = (float)exp(-(double)j * (9.210340371976182736 / 32.0));
    float sn, c;
    sincosf((float)s * inv, &sn, &c);
    tab[(size_t)s * 64 + 2 * j] = c;
    tab[(size_t)s * 64 + 2 * j + 1] = sn;
  }
}

// ---------------------------------------------------------------------------
// bf16 MFMA GEMM (round-6 proven inner loop; ONE change: XCD-aware decode).
// Old decode bx=flat&7, by=flat>>3 put the 8 blocks sharing an A-row-panel on
// 8 DIFFERENT XCDs (XCD=blk%8) -> every per-XCD L2 refetched nearly all of A
// (round-4 FETCH 101 MB vs ~26 ideal). New decode bx=flat>>6, by=flat&63 ->
// XCD = (bx*64+by)%8 = by%8: same-by blocks share one XCD, A fetched once per
// XCD. Predicted FETCH ~30 MB.
// Tile 64(M)x128(N), BK=64 as two 32-halves, 24 KB LDS, grid 512(+128 q0).
// ---------------------------------------------------------------------------
#define GM 64
#define GN 128

__global__ __launch_bounds__(256) void gemm_bf16(
    const unsigned short* __restrict__ A, const unsigned short* __restrict__ BT,
    const float* __restrict__ bias, unsigned short* __restrict__ C,
    const float* __restrict__ Wq, float* __restrict__ part, int nGemmBlocks) {
  __shared__ __align__(16) unsigned short As[2][GM * 32];   // 8 KB
  __shared__ __align__(16) unsigned short Bs[2][GN * 32];   // 16 KB
  __shared__ float gs[4][32];

  const int flat = blockIdx.x;
  const int tid  = threadIdx.x;

  if (flat >= nGemmBlocks) {
    // ---- fused q0 partial: part[(slab*4+b)*D+n] = sum_k g[b,0,k]*Wq[k,n]
    // (lightweight: 32-k slab per block, coalesced Wq rows — round-6 proven)
    const int qb = flat - nGemmBlocks;   // 0..127
    const int slab = qb >> 2;            // 0..31
    const int n = (qb & 3) * 256 + tid;  // 0..1023
    if (tid < 128) {
      const int b = tid >> 5, kk = tid & 31;
      gs[b][kk] = bf2f(A[(size_t)b * S_ * D_ + slab * 32 + kk]);
    }
    __syncthreads();
    float a0 = 0.f, a1 = 0.f, a2 = 0.f, a3 = 0.f;
#pragma unroll
    for (int kk = 0; kk < 32; ++kk) {
      const float w = Wq[(size_t)(slab * 32 + kk) * D_ + n];
      a0 = fmaf(gs[0][kk], w, a0);
      a1 = fmaf(gs[1][kk], w, a1);
      a2 = fmaf(gs[2][kk], w, a2);
      a3 = fmaf(gs[3][kk], w, a3);
    }
    part[(size_t)(slab * 4 + 0) * D_ + n] = a0;
    part[(size_t)(slab * 4 + 1) * D_ + n] = a1;
    part[(size_t)(slab * 4 + 2) * D_ + n] = a2;
    part[(size_t)(slab * 4 + 3) * D_ + n] = a3;
    return;
  }

  // ---- GEMM path: XCD-aware decode (the round-10 change) ----
  const int bx = flat >> 6;       // N tiles: 8   (was flat & 7)
  const int by = flat & 63;       // M tiles: 64  (was flat >> 3)
  const int wv   = tid >> 6;
  const int lane = tid & 63;
  const int m0 = by * GM;
  const int n0 = bx * GN;

  // staging: 16 rows x 64B per glds; row = lane>>2, col = (lane&3)*8 elems
  const int colOff = (lane & 3) * 8;
  const size_t aOff  = (size_t)(m0 + 16 * wv + (lane >> 2)) * 1024 + colOff;
  const size_t bOff0 = (size_t)(n0 + 32 * wv + (lane >> 2)) * 1024 + colOff;
  const size_t bOff1 = bOff0 + (size_t)16 * 1024;

  const int l15  = lane & 15;
  const int quad = lane >> 4;

  f32x4 acc[4][2];
#pragma unroll
  for (int i = 0; i < 4; ++i)
#pragma unroll
    for (int j = 0; j < 2; ++j) acc[i][j] = (f32x4){0.f, 0.f, 0.f, 0.f};

#pragma unroll 1
  for (int k0 = 0; k0 < 1024; k0 += 64) {
    __syncthreads();                      // prior LDS reads done
#pragma unroll
    for (int ks = 0; ks < 2; ++ks) {
      gl_lds16(A  + aOff  + k0 + ks * 32, &As[ks][wv * 512]);
      gl_lds16(BT + bOff0 + k0 + ks * 32, &Bs[ks][wv * 1024]);
      gl_lds16(BT + bOff1 + k0 + ks * 32, &Bs[ks][wv * 1024 + 512]);
    }
    __syncthreads();                      // vmcnt drain: LDS writes visible

#pragma unroll
    for (int ks = 0; ks < 2; ++ks) {
      bf16x8 af[4], bfr[2];
#pragma unroll
      for (int mi = 0; mi < 4; ++mi)
        af[mi] = *(const bf16x8*)(&As[ks][(mi * 16 + l15) * 32 + quad * 8]);
#pragma unroll
      for (int ni = 0; ni < 2; ++ni)
        bfr[ni] =
            *(const bf16x8*)(&Bs[ks][(wv * 32 + ni * 16 + l15) * 32 + quad * 8]);
#pragma unroll
      for (int mi = 0; mi < 4; ++mi)
#pragma unroll
        for (int ni = 0; ni < 2; ++ni)
          acc[mi][ni] = __builtin_amdgcn_mfma_f32_16x16x32_bf16(
              af[mi], bfr[ni], acc[mi][ni], 0, 0, 0);
    }
  }

  // epilogue: C/D layout col = lane&15, row = quad*4 + r (m89/m91 verified)
#pragma unroll
  for (int ni = 0; ni < 2; ++ni) {
    const int n = n0 + wv * 32 + ni * 16 + l15;
    const float bv = bias[n];
#pragma unroll
    for (int mi = 0; mi < 4; ++mi) {
#pragma unroll
      for (int r = 0; r < 4; ++r) {
        const int m = m0 + mi * 16 + quad * 4 + r;
        C[(size_t)m * 1024 + n] = f2bf(acc[mi][ni][r] + bv);
      }
    }
  }
}

// ---------------------------------------------------------------------------
// Attention row-0 scores (round-6 verbatim): 8 lanes share one s-row,
// butterfly-reduce over width 8. Block = (b,h,chunk of 32 s); grid 2048.
// ---------------------------------------------------------------------------
__global__ __launch_bounds__(256) void attn_scores_kernel(
    const unsigned short* __restrict__ Kbf, const float* __restrict__ part,
    const float* __restrict__ bq, const float* __restrict__ tab,
    const int* __restrict__ mask, float* __restrict__ scores,
    float* __restrict__ mS) {
  const int bi = blockIdx.x;
  const int b = bi >> 9;
  const int h = (bi >> 5) & 15;
  const int chunk = bi & 31;
  const int tid = threadIdx.x;
  const int bh = b * H_ + h;
  const int sl = tid >> 3;  // 0..31
  const int j  = tid & 7;   // 16B chunk within the 64-elem row
  const int s  = chunk * 32 + sl;

  __shared__ float q0s[DK_];
  __shared__ float wredm[4];
  __shared__ float wreds[4];

  if (tid < 64) {
    const int n = h * DK_ + tid;
    float v = bq[n];
#pragma unroll
    for (int sl2 = 0; sl2 < 32; ++sl2)
      v += part[(size_t)(sl2 * 4 + b) * D_ + n];
    q0s[tid] = v;
  }
  __syncthreads();

  const ushort4* kp =
      (const ushort4*)(Kbf + ((size_t)(b * S_ + s)) * D_ + h * DK_ + j * 8);
  const ushort4 k0 = kp[0], k1 = kp[1];
  const float4* tb = (const float4*)(tab + (size_t)s * 64 + j * 8);
  const float4 t0 = tb[0], t1 = tb[1];

  float dot = 0.f;
  {
    const float ka = bf2f(k0.x), kb = bf2f(k0.y);
    dot += q0s[j * 8 + 0] * (ka * t0.x - kb * t0.y) +
           q0s[j * 8 + 1] * (kb * t0.x + ka * t0.y);
  }
  {
    const float ka = bf2f(k0.z), kb = bf2f(k0.w);
    dot += q0s[j * 8 + 2] * (ka * t0.z - kb * t0.w) +
           q0s[j * 8 + 3] * (kb * t0.z + ka * t0.w);
  }
  {
    const float ka = bf2f(k1.x), kb = bf2f(k1.y);
    dot += q0s[j * 8 + 4] * (ka * t1.x - kb * t1.y) +
           q0s[j * 8 + 5] * (kb * t1.x + ka * t1.y);
  }
  {
    const float ka = bf2f(k1.z), kb = bf2f(k1.w);
    dot += q0s[j * 8 + 6] * (ka * t1.z - kb * t1.w) +
           q0s[j * 8 + 7] * (kb * t1.z + ka * t1.w);
  }
  dot += __shfl_xor(dot, 1);
  dot += __shfl_xor(dot, 2);
  dot += __shfl_xor(dot, 4);
  dot *= 0.125f;  // 1/sqrt(64)
  if (mask[b * S_ + s] == 0) dot = -1e9f;
  if (j == 0) scores[(size_t)bh * S_ + s] = dot;

  float mx = dot;
#pragma unroll
  for (int off = 8; off < 64; off <<= 1) mx = fmaxf(mx, __shfl_xor(mx, off));
  if ((tid & 63) == 0) wredm[tid >> 6] = mx;
  __syncthreads();
  mx = fmaxf(fmaxf(wredm[0], wredm[1]), fmaxf(wredm[2], wredm[3]));

  float e = (j == 0) ? expf(dot - mx) : 0.f;
#pragma unroll
  for (int off = 1; off < 64; off <<= 1) e += __shfl_xor(e, off);
  if ((tid & 63) == 0) wreds[tid >> 6] = e;
  __syncthreads();
  if (tid == 0) {
    mS[(size_t)(bh * 32 + chunk) * 2 + 0] = mx;
    mS[(size_t)(bh * 32 + chunk) * 2 + 1] =
        wreds[0] + wreds[1] + wreds[2] + wreds[3];
  }
}

// ---------------------------------------------------------------------------
// Conv1d + bias + ReLU with fused softmax combine (round-6 verbatim).
// ---------------------------------------------------------------------------
__global__ __launch_bounds__(256) void conv_norm_relu_kernel(
    const float* __restrict__ scores, const float* __restrict__ mS,
    const float* __restrict__ cw, const float* __restrict__ cb,
    float* __restrict__ out) {
  const int b = blockIdx.y;
  const int s0 = blockIdx.x * 16;
  const int oz = blockIdx.z * 256;
  const int tid = threadIdx.x;

  __shared__ float msh[16], ish[16];
  __shared__ float sm[16][18];  // normalized p, [c][s0-1 .. s0+16]

  if (tid < 16) {
    const int bh = b * H_ + tid;
    float m = -3e38f;
#pragma unroll
    for (int c = 0; c < 32; ++c)
      m = fmaxf(m, mS[(size_t)(bh * 32 + c) * 2]);
    float S = 0.f;
#pragma unroll
    for (int c = 0; c < 32; ++c)
      S += mS[(size_t)(bh * 32 + c) * 2 + 1] *
           expf(mS[(size_t)(bh * 32 + c) * 2] - m);
    msh[tid] = m;
    ish[tid] = 1.f / S;
  }
  __syncthreads();

  for (int i = tid; i < 16 * 18; i += 256) {
    const int c = i / 18, ss = i % 18;
    const int gs = s0 - 1 + ss;
    float p = 0.f;
    if (gs >= 0 && gs < S_) {
      const int bh = b * H_ + c;
      p = expf(scores[(size_t)bh * S_ + gs] - msh[c]) * ish[c];
    }
    sm[c][ss] = p;
  }
  __syncthreads();

  const int og = tid >> 4;  // 0..15
  const int si = tid & 15;  // 0..15

  float r[16][3];
#pragma unroll
  for (int c = 0; c < 16; ++c) {
    r[c][0] = sm[c][si + 0];
    r[c][1] = sm[c][si + 1];
    r[c][2] = sm[c][si + 2];
  }

#pragma unroll 1
  for (int i = 0; i < 16; ++i) {
    const int o = oz + i * 16 + og;
    const float4* wo = (const float4*)(cw + (size_t)o * 48);
    float accv = cb[o];
#pragma unroll
    for (int q = 0; q < 12; ++q) {
      const float4 w4 = wo[q];
      const int f0 = q * 4;
      accv = fmaf(r[(f0 + 0) / 3][(f0 + 0) % 3], w4.x, accv);
      accv = fmaf(r[(f0 + 1) / 3][(f0 + 1) % 3], w4.y, accv);
      accv = fmaf(r[(f0 + 2) / 3][(f0 + 2) % 3], w4.z, accv);
      accv = fmaf(r[(f0 + 3) / 3][(f0 + 3) % 3], w4.w, accv);
    }
    out[((size_t)b * D_ + o) * S_ + s0 + si] = fmaxf(accv, 0.f);
  }
}

// ---------------------------------------------------------------------------
// Workspace (round-6 layout, peak ~29.1 MB):
//  [ 0, 8M) Xbf | [8,16M) G | [16,24M) Kbf | [24,26M) WGT | [26,28M) WkT
//  [28M,+512K) part | +256K ropeT | +256K scores | +16K mS
// ---------------------------------------------------------------------------
extern "C" void kernel_launch(void* const* d_in, const int* in_sizes, int n_in,
                              void* d_out, int out_size, void* d_ws,
                              size_t ws_size, hipStream_t stream) {
  const float* x    = (const float*)d_in[0];
  const int*   mask = (const int*)d_in[1];
  const float* W_G  = (const float*)d_in[2];
  const float* b_G  = (const float*)d_in[3];
  const float* Wq   = (const float*)d_in[4];
  const float* bq   = (const float*)d_in[5];
  const float* Wk   = (const float*)d_in[6];
  const float* bk   = (const float*)d_in[7];
  const float* cw   = (const float*)d_in[8];
  const float* cb   = (const float*)d_in[9];
  float* out = (float*)d_out;

  char* ws = (char*)d_ws;
  unsigned short* Xbf = (unsigned short*)(ws);
  unsigned short* G   = (unsigned short*)(ws + (8u << 20));
  unsigned short* Kbf = (unsigned short*)(ws + (16u << 20));
  unsigned short* WGT = (unsigned short*)(ws + (24u << 20));
  unsigned short* WkT = (unsigned short*)(ws + (26u << 20));
  float* part   = (float*)(ws + (28u << 20));
  float* ropeT  = (float*)(ws + (28u << 20) + (512u << 10));
  float* scores = (float*)(ws + (28u << 20) + (768u << 10));
  float* mS     = (float*)(ws + (28u << 20) + (1024u << 10));

  prep_kernel<<<4224, 256, 0, stream>>>(x, W_G, Wk, Xbf, WGT, WkT, ropeT);
  gemm_bf16<<<512, 256, 0, stream>>>(Xbf, WGT, b_G, G, nullptr, nullptr, 512);
  gemm_bf16<<<640, 256, 0, stream>>>(G, WkT, bk, Kbf, Wq, part, 512);
  attn_scores_kernel<<<2048, 256, 0, stream>>>(Kbf, part, bq, ropeT, mask,
                                               scores, mS);
  conv_norm_relu_kernel<<<dim3(S_ / 16, B_, 4), 256, 0, stream>>>(
      scores, mS, cw, cb, out);
}

// Round 11
// 157.113 us; speedup vs baseline: 2.7098x; 1.0212x over previous
//
#include <hip/hip_runtime.h>
#include <math.h>

// Problem constants
#define B_  4
#define S_  1024
#define D_  1024
#define H_  16
#define DK_ 64
#define M_  (B_ * S_)   // 4096 rows for the big GEMMs

typedef __bf16 bf16x8 __attribute__((ext_vector_type(8)));
typedef float  f32x4  __attribute__((ext_vector_type(4)));

// ---- bf16 helpers (RNE) ----------------------------------------------------
__device__ __forceinline__ unsigned short f2bf(float f) {
  unsigned u = __builtin_bit_cast(unsigned, f);
  u = (u + 0x7FFFu + ((u >> 16) & 1u)) >> 16;
  return (unsigned short)u;
}
__device__ __forceinline__ float bf2f(unsigned short h) {
  unsigned u = ((unsigned)h) << 16;
  return __builtin_bit_cast(float, u);
}

// async global->LDS, 16 B per lane; LDS dest = wave-uniform base + lane*16
__device__ __forceinline__ void gl_lds16(const void* g, void* lds) {
  __builtin_amdgcn_global_load_lds(
      (const __attribute__((address_space(1))) unsigned int*)(unsigned long long)g,
      (__attribute__((address_space(3))) unsigned int*)(unsigned int)(unsigned long long)lds,
      16, 0, 0);
}

// ---------------------------------------------------------------------------
// PREP (round-6 verbatim):
//  blocks [0,2048):    X fp32 -> bf16 cast (8 elems/thread)
//  blocks [2048,3072): W_G transpose+cast -> WGT bf16 [n][k]
//  blocks [3072,4096): Wk  transpose+cast -> WkT bf16 [n][k]
//  blocks [4096,4224): RoPE table tab[s*64+2j]=cos(s*inv_j), +1 = sin
// ---------------------------------------------------------------------------
__global__ __launch_bounds__(256) void prep_kernel(
    const float* __restrict__ X, const float* __restrict__ W_G,
    const float* __restrict__ Wk, unsigned short* __restrict__ Xbf,
    unsigned short* __restrict__ WGT, unsigned short* __restrict__ WkT,
    float* __restrict__ tab) {
  __shared__ float tle[32][33];
  const int blk = blockIdx.x;
  const int tid = threadIdx.x;

  if (blk < 2048) {
    const int i = (blk * 256 + tid) * 2;  // float4 index
    const float4 v0 = ((const float4*)X)[i];
    const float4 v1 = ((const float4*)X)[i + 1];
    ushort4 h0, h1;
    h0.x = f2bf(v0.x); h0.y = f2bf(v0.y); h0.z = f2bf(v0.z); h0.w = f2bf(v0.w);
    h1.x = f2bf(v1.x); h1.y = f2bf(v1.y); h1.z = f2bf(v1.z); h1.w = f2bf(v1.w);
    ((ushort4*)Xbf)[i] = h0;
    ((ushort4*)Xbf)[i + 1] = h1;
  } else if (blk < 4096) {
    const bool isG = blk < 3072;
    const float* W = isG ? W_G : Wk;
    unsigned short* WT = isG ? WGT : WkT;
    const int t = isG ? blk - 2048 : blk - 3072;
    const int k0 = (t & 31) * 32;
    const int n0 = (t >> 5) * 32;
    const int tx = tid & 31;
    const int ty = tid >> 5;  // 0..7
#pragma unroll
    for (int r = 0; r < 32; r += 8)
      tle[ty + r][tx] = W[(size_t)(k0 + ty + r) * 1024 + n0 + tx];
    __syncthreads();
#pragma unroll
    for (int r = 0; r < 32; r += 8)
      WT[(size_t)(n0 + ty + r) * 1024 + k0 + tx] = f2bf(tle[tx][ty + r]);
  } else {
    const int idx = (blk - 4096) * 256 + tid;
    const int s = idx >> 5, j = idx & 31;
    const float inv = (float)exp(-(double)j * (9.210340371976182736 / 32.0));
    float sn, c;
    sincosf((float)s * inv, &sn, &c);
    tab[(size_t)s * 64 + 2 * j] = c;
    tab[(size_t)s * 64 + 2 * j + 1] = sn;
  }
}

// ---------------------------------------------------------------------------
// bf16 MFMA GEMM (round-10 verbatim: proven inner loop + XCD-aware decode
// bx=flat>>6, by=flat&63 so same-A-panel blocks share an XCD; FETCH ~3x lower).
// Tile 64(M)x128(N), BK=64 as two 32-halves, 24 KB LDS, grid 512(+128 q0).
// ---------------------------------------------------------------------------
#define GM 64
#define GN 128

__global__ __launch_bounds__(256) void gemm_bf16(
    const unsigned short* __restrict__ A, const unsigned short* __restrict__ BT,
    const float* __restrict__ bias, unsigned short* __restrict__ C,
    const float* __restrict__ Wq, float* __restrict__ part, int nGemmBlocks) {
  __shared__ __align__(16) unsigned short As[2][GM * 32];   // 8 KB
  __shared__ __align__(16) unsigned short Bs[2][GN * 32];   // 16 KB
  __shared__ float gs[4][32];

  const int flat = blockIdx.x;
  const int tid  = threadIdx.x;

  if (flat >= nGemmBlocks) {
    // ---- fused q0 partial: part[(slab*4+b)*D+n] = sum_k g[b,0,k]*Wq[k,n]
    const int qb = flat - nGemmBlocks;   // 0..127
    const int slab = qb >> 2;            // 0..31
    const int n = (qb & 3) * 256 + tid;  // 0..1023
    if (tid < 128) {
      const int b = tid >> 5, kk = tid & 31;
      gs[b][kk] = bf2f(A[(size_t)b * S_ * D_ + slab * 32 + kk]);
    }
    __syncthreads();
    float a0 = 0.f, a1 = 0.f, a2 = 0.f, a3 = 0.f;
#pragma unroll
    for (int kk = 0; kk < 32; ++kk) {
      const float w = Wq[(size_t)(slab * 32 + kk) * D_ + n];
      a0 = fmaf(gs[0][kk], w, a0);
      a1 = fmaf(gs[1][kk], w, a1);
      a2 = fmaf(gs[2][kk], w, a2);
      a3 = fmaf(gs[3][kk], w, a3);
    }
    part[(size_t)(slab * 4 + 0) * D_ + n] = a0;
    part[(size_t)(slab * 4 + 1) * D_ + n] = a1;
    part[(size_t)(slab * 4 + 2) * D_ + n] = a2;
    part[(size_t)(slab * 4 + 3) * D_ + n] = a3;
    return;
  }

  // ---- GEMM path (XCD-aware decode) ----
  const int bx = flat >> 6;       // N tiles: 8
  const int by = flat & 63;       // M tiles: 64
  const int wv   = tid >> 6;
  const int lane = tid & 63;
  const int m0 = by * GM;
  const int n0 = bx * GN;

  const int colOff = (lane & 3) * 8;
  const size_t aOff  = (size_t)(m0 + 16 * wv + (lane >> 2)) * 1024 + colOff;
  const size_t bOff0 = (size_t)(n0 + 32 * wv + (lane >> 2)) * 1024 + colOff;
  const size_t bOff1 = bOff0 + (size_t)16 * 1024;

  const int l15  = lane & 15;
  const int quad = lane >> 4;

  f32x4 acc[4][2];
#pragma unroll
  for (int i = 0; i < 4; ++i)
#pragma unroll
    for (int j = 0; j < 2; ++j) acc[i][j] = (f32x4){0.f, 0.f, 0.f, 0.f};

#pragma unroll 1
  for (int k0 = 0; k0 < 1024; k0 += 64) {
    __syncthreads();                      // prior LDS reads done
#pragma unroll
    for (int ks = 0; ks < 2; ++ks) {
      gl_lds16(A  + aOff  + k0 + ks * 32, &As[ks][wv * 512]);
      gl_lds16(BT + bOff0 + k0 + ks * 32, &Bs[ks][wv * 1024]);
      gl_lds16(BT + bOff1 + k0 + ks * 32, &Bs[ks][wv * 1024 + 512]);
    }
    __syncthreads();                      // vmcnt drain: LDS writes visible

#pragma unroll
    for (int ks = 0; ks < 2; ++ks) {
      bf16x8 af[4], bfr[2];
#pragma unroll
      for (int mi = 0; mi < 4; ++mi)
        af[mi] = *(const bf16x8*)(&As[ks][(mi * 16 + l15) * 32 + quad * 8]);
#pragma unroll
      for (int ni = 0; ni < 2; ++ni)
        bfr[ni] =
            *(const bf16x8*)(&Bs[ks][(wv * 32 + ni * 16 + l15) * 32 + quad * 8]);
#pragma unroll
      for (int mi = 0; mi < 4; ++mi)
#pragma unroll
        for (int ni = 0; ni < 2; ++ni)
          acc[mi][ni] = __builtin_amdgcn_mfma_f32_16x16x32_bf16(
              af[mi], bfr[ni], acc[mi][ni], 0, 0, 0);
    }
  }

  // epilogue: C/D layout col = lane&15, row = quad*4 + r (m89/m91 verified)
#pragma unroll
  for (int ni = 0; ni < 2; ++ni) {
    const int n = n0 + wv * 32 + ni * 16 + l15;
    const float bv = bias[n];
#pragma unroll
    for (int mi = 0; mi < 4; ++mi) {
#pragma unroll
      for (int r = 0; r < 4; ++r) {
        const int m = m0 + mi * 16 + quad * 4 + r;
        C[(size_t)m * 1024 + n] = f2bf(acc[mi][ni][r] + bv);
      }
    }
  }
}

// ---------------------------------------------------------------------------
// Attention row-0 scores (round-6 verbatim).
// ---------------------------------------------------------------------------
__global__ __launch_bounds__(256) void attn_scores_kernel(
    const unsigned short* __restrict__ Kbf, const float* __restrict__ part,
    const float* __restrict__ bq, const float* __restrict__ tab,
    const int* __restrict__ mask, float* __restrict__ scores,
    float* __restrict__ mS) {
  const int bi = blockIdx.x;
  const int b = bi >> 9;
  const int h = (bi >> 5) & 15;
  const int chunk = bi & 31;
  const int tid = threadIdx.x;
  const int bh = b * H_ + h;
  const int sl = tid >> 3;  // 0..31
  const int j  = tid & 7;   // 16B chunk within the 64-elem row
  const int s  = chunk * 32 + sl;

  __shared__ float q0s[DK_];
  __shared__ float wredm[4];
  __shared__ float wreds[4];

  if (tid < 64) {
    const int n = h * DK_ + tid;
    float v = bq[n];
#pragma unroll
    for (int sl2 = 0; sl2 < 32; ++sl2)
      v += part[(size_t)(sl2 * 4 + b) * D_ + n];
    q0s[tid] = v;
  }
  __syncthreads();

  const ushort4* kp =
      (const ushort4*)(Kbf + ((size_t)(b * S_ + s)) * D_ + h * DK_ + j * 8);
  const ushort4 k0 = kp[0], k1 = kp[1];
  const float4* tb = (const float4*)(tab + (size_t)s * 64 + j * 8);
  const float4 t0 = tb[0], t1 = tb[1];

  float dot = 0.f;
  {
    const float ka = bf2f(k0.x), kb = bf2f(k0.y);
    dot += q0s[j * 8 + 0] * (ka * t0.x - kb * t0.y) +
           q0s[j * 8 + 1] * (kb * t0.x + ka * t0.y);
  }
  {
    const float ka = bf2f(k0.z), kb = bf2f(k0.w);
    dot += q0s[j * 8 + 2] * (ka * t0.z - kb * t0.w) +
           q0s[j * 8 + 3] * (kb * t0.z + ka * t0.w);
  }
  {
    const float ka = bf2f(k1.x), kb = bf2f(k1.y);
    dot += q0s[j * 8 + 4] * (ka * t1.x - kb * t1.y) +
           q0s[j * 8 + 5] * (kb * t1.x + ka * t1.y);
  }
  {
    const float ka = bf2f(k1.z), kb = bf2f(k1.w);
    dot += q0s[j * 8 + 6] * (ka * t1.z - kb * t1.w) +
           q0s[j * 8 + 7] * (kb * t1.z + ka * t1.w);
  }
  dot += __shfl_xor(dot, 1);
  dot += __shfl_xor(dot, 2);
  dot += __shfl_xor(dot, 4);
  dot *= 0.125f;  // 1/sqrt(64)
  if (mask[b * S_ + s] == 0) dot = -1e9f;
  if (j == 0) scores[(size_t)bh * S_ + s] = dot;

  float mx = dot;
#pragma unroll
  for (int off = 8; off < 64; off <<= 1) mx = fmaxf(mx, __shfl_xor(mx, off));
  if ((tid & 63) == 0) wredm[tid >> 6] = mx;
  __syncthreads();
  mx = fmaxf(fmaxf(wredm[0], wredm[1]), fmaxf(wredm[2], wredm[3]));

  float e = (j == 0) ? expf(dot - mx) : 0.f;
#pragma unroll
  for (int off = 1; off < 64; off <<= 1) e += __shfl_xor(e, off);
  if ((tid & 63) == 0) wreds[tid >> 6] = e;
  __syncthreads();
  if (tid == 0) {
    mS[(size_t)(bh * 32 + chunk) * 2 + 0] = mx;
    mS[(size_t)(bh * 32 + chunk) * 2 + 1] =
        wreds[0] + wreds[1] + wreds[2] + wreds[3];
  }
}

// ---------------------------------------------------------------------------
// Conv1d (16->1024, k=3, pad=1) + bias + ReLU — ROUND-11 REWRITE.
// Round-10 version: 44.7 us, VALUBusy 17%, 83% stall; stores were 4x64B
// scattered per wave with out-cachelines split across blocks/XCDs, and
// weights re-fetched from cache every o-step under #pragma unroll 1.
// New: block = (s-tile 64, b, o-tile 64), grid (16,4,16)=1024.
//  - weights (12 KB) + cb + normalized p-halo staged in LDS once
//  - wave = one o across 64 contiguous s per iter: 12 uniform ds_read_b128
//    (broadcast, conflict-free) + 48 FMA + ONE 256B contiguous store
//  - each 128B out-line written wholly by one block (no cross-XCD splits)
// Same summation order (c-major, t-minor, bias first) -> bitwise-same output.
// ---------------------------------------------------------------------------
__global__ __launch_bounds__(256) void conv_norm_relu_kernel(
    const float* __restrict__ scores, const float* __restrict__ mS,
    const float* __restrict__ cw, const float* __restrict__ cb,
    float* __restrict__ out) {
  const int b  = blockIdx.y;
  const int s0 = blockIdx.x * 64;
  const int o0 = blockIdx.z * 64;
  const int tid = threadIdx.x;

  __shared__ float msh[16], ish[16];
  __shared__ __align__(16) float wsm[64 * 48];  // 12 KB, row = 192B (16B-align)
  __shared__ float cbs[64];
  __shared__ float sm[16][66];                  // p, [c][s0-1 .. s0+64]

  // softmax combine (round-6 proven), overlapped with the weight copy below
  if (tid < 16) {
    const int bh = b * H_ + tid;
    float m = -3e38f;
#pragma unroll
    for (int c = 0; c < 32; ++c)
      m = fmaxf(m, mS[(size_t)(bh * 32 + c) * 2]);
    float S = 0.f;
#pragma unroll
    for (int c = 0; c < 32; ++c)
      S += mS[(size_t)(bh * 32 + c) * 2 + 1] *
           expf(mS[(size_t)(bh * 32 + c) * 2] - m);
    msh[tid] = m;
    ish[tid] = 1.f / S;
  }
  // weight tile: contiguous 3072-float copy (coalesced)
  for (int i = tid; i < 64 * 48; i += 256) wsm[i] = cw[(size_t)o0 * 48 + i];
  if (tid < 64) cbs[tid] = cb[o0 + tid];
  __syncthreads();  // msh/ish ready

  for (int i = tid; i < 16 * 66; i += 256) {
    const int c = i / 66, ss = i % 66;
    const int gs = s0 - 1 + ss;
    sm[c][ss] = (gs >= 0 && gs < S_)
                    ? expf(scores[(size_t)(b * H_ + c) * S_ + gs] - msh[c]) *
                          ish[c]
                    : 0.f;
  }
  __syncthreads();

  const int w = tid >> 6;   // wave 0..3
  const int l = tid & 63;   // s lane
  float r[16][3];
#pragma unroll
  for (int c = 0; c < 16; ++c) {
    r[c][0] = sm[c][l + 0];
    r[c][1] = sm[c][l + 1];
    r[c][2] = sm[c][l + 2];
  }

  float* outRow = out + ((size_t)b * D_ + o0) * S_ + s0 + l;
#pragma unroll 2
  for (int i = 0; i < 16; ++i) {
    const int ol = i * 4 + w;                 // wave-uniform o index
    const float* wr = &wsm[ol * 48];          // uniform row -> LDS broadcast
    float acc = cbs[ol];
#pragma unroll
    for (int c = 0; c < 16; ++c) {
      acc = fmaf(r[c][0], wr[c * 3 + 0], acc);
      acc = fmaf(r[c][1], wr[c * 3 + 1], acc);
      acc = fmaf(r[c][2], wr[c * 3 + 2], acc);
    }
    outRow[(size_t)ol * S_] = fmaxf(acc, 0.f);  // 256B contiguous per wave
  }
}

// ---------------------------------------------------------------------------
// Workspace (round-6 layout, peak ~29.1 MB):
//  [ 0, 8M) Xbf | [8,16M) G | [16,24M) Kbf | [24,26M) WGT | [26,28M) WkT
//  [28M,+512K) part | +256K ropeT | +256K scores | +16K mS
// ---------------------------------------------------------------------------
extern "C" void kernel_launch(void* const* d_in, const int* in_sizes, int n_in,
                              void* d_out, int out_size, void* d_ws,
                              size_t ws_size, hipStream_t stream) {
  const float* x    = (const float*)d_in[0];
  const int*   mask = (const int*)d_in[1];
  const float* W_G  = (const float*)d_in[2];
  const float* b_G  = (const float*)d_in[3];
  const float* Wq   = (const float*)d_in[4];
  const float* bq   = (const float*)d_in[5];
  const float* Wk   = (const float*)d_in[6];
  const float* bk   = (const float*)d_in[7];
  const float* cw   = (const float*)d_in[8];
  const float* cb   = (const float*)d_in[9];
  float* out = (float*)d_out;

  char* ws = (char*)d_ws;
  unsigned short* Xbf = (unsigned short*)(ws);
  unsigned short* G   = (unsigned short*)(ws + (8u << 20));
  unsigned short* Kbf = (unsigned short*)(ws + (16u << 20));
  unsigned short* WGT = (unsigned short*)(ws + (24u << 20));
  unsigned short* WkT = (unsigned short*)(ws + (26u << 20));
  float* part   = (float*)(ws + (28u << 20));
  float* ropeT  = (float*)(ws + (28u << 20) + (512u << 10));
  float* scores = (float*)(ws + (28u << 20) + (768u << 10));
  float* mS     = (float*)(ws + (28u << 20) + (1024u << 10));

  prep_kernel<<<4224, 256, 0, stream>>>(x, W_G, Wk, Xbf, WGT, WkT, ropeT);
  gemm_bf16<<<512, 256, 0, stream>>>(Xbf, WGT, b_G, G, nullptr, nullptr, 512);
  gemm_bf16<<<640, 256, 0, stream>>>(G, WkT, bk, Kbf, Wq, part, 512);
  attn_scores_kernel<<<2048, 256, 0, stream>>>(Kbf, part, bq, ropeT, mask,
                                               scores, mS);
  conv_norm_relu_kernel<<<dim3(16, B_, 16), 256, 0, stream>>>(
      scores, mS, cw, cb, out);
}

// Round 12
// 153.390 us; speedup vs baseline: 2.7756x; 1.0243x over previous
//
#include <hip/hip_runtime.h>
#include <math.h>

// Problem constants
#define B_  4
#define S_  1024
#define D_  1024
#define H_  16
#define DK_ 64
#define M_  (B_ * S_)   // 4096 rows for the big GEMMs

typedef __bf16 bf16x8 __attribute__((ext_vector_type(8)));
typedef float  f32x4  __attribute__((ext_vector_type(4)));

// ---- bf16 helpers (RNE) ----------------------------------------------------
__device__ __forceinline__ unsigned short f2bf(float f) {
  unsigned u = __builtin_bit_cast(unsigned, f);
  u = (u + 0x7FFFu + ((u >> 16) & 1u)) >> 16;
  return (unsigned short)u;
}
__device__ __forceinline__ float bf2f(unsigned short h) {
  unsigned u = ((unsigned)h) << 16;
  return __builtin_bit_cast(float, u);
}

// async global->LDS, 16 B per lane; LDS dest = wave-uniform base + lane*16
__device__ __forceinline__ void gl_lds16(const void* g, void* lds) {
  __builtin_amdgcn_global_load_lds(
      (const __attribute__((address_space(1))) unsigned int*)(unsigned long long)g,
      (__attribute__((address_space(3))) unsigned int*)(unsigned int)(unsigned long long)lds,
      16, 0, 0);
}

// ---------------------------------------------------------------------------
// PREP (round-6 verbatim):
//  blocks [0,2048):    X fp32 -> bf16 cast (8 elems/thread)
//  blocks [2048,3072): W_G transpose+cast -> WGT bf16 [n][k]
//  blocks [3072,4096): Wk  transpose+cast -> WkT bf16 [n][k]
//  blocks [4096,4224): RoPE table tab[s*64+2j]=cos(s*inv_j), +1 = sin
// ---------------------------------------------------------------------------
__global__ __launch_bounds__(256) void prep_kernel(
    const float* __restrict__ X, const float* __restrict__ W_G,
    const float* __restrict__ Wk, unsigned short* __restrict__ Xbf,
    unsigned short* __restrict__ WGT, unsigned short* __restrict__ WkT,
    float* __restrict__ tab) {
  __shared__ float tle[32][33];
  const int blk = blockIdx.x;
  const int tid = threadIdx.x;

  if (blk < 2048) {
    const int i = (blk * 256 + tid) * 2;  // float4 index
    const float4 v0 = ((const float4*)X)[i];
    const float4 v1 = ((const float4*)X)[i + 1];
    ushort4 h0, h1;
    h0.x = f2bf(v0.x); h0.y = f2bf(v0.y); h0.z = f2bf(v0.z); h0.w = f2bf(v0.w);
    h1.x = f2bf(v1.x); h1.y = f2bf(v1.y); h1.z = f2bf(v1.z); h1.w = f2bf(v1.w);
    ((ushort4*)Xbf)[i] = h0;
    ((ushort4*)Xbf)[i + 1] = h1;
  } else if (blk < 4096) {
    const bool isG = blk < 3072;
    const float* W = isG ? W_G : Wk;
    unsigned short* WT = isG ? WGT : WkT;
    const int t = isG ? blk - 2048 : blk - 3072;
    const int k0 = (t & 31) * 32;
    const int n0 = (t >> 5) * 32;
    const int tx = tid & 31;
    const int ty = tid >> 5;  // 0..7
#pragma unroll
    for (int r = 0; r < 32; r += 8)
      tle[ty + r][tx] = W[(size_t)(k0 + ty + r) * 1024 + n0 + tx];
    __syncthreads();
#pragma unroll
    for (int r = 0; r < 32; r += 8)
      WT[(size_t)(n0 + ty + r) * 1024 + k0 + tx] = f2bf(tle[tx][ty + r]);
  } else {
    const int idx = (blk - 4096) * 256 + tid;
    const int s = idx >> 5, j = idx & 31;
    const float inv = (float)exp(-(double)j * (9.210340371976182736 / 32.0));
    float sn, c;
    sincosf((float)s * inv, &sn, &c);
    tab[(size_t)s * 64 + 2 * j] = c;
    tab[(size_t)s * 64 + 2 * j + 1] = sn;
  }
}

// ---------------------------------------------------------------------------
// bf16 MFMA GEMM (round-10/11 verbatim: proven inner loop + XCD-aware decode).
// ---------------------------------------------------------------------------
#define GM 64
#define GN 128

__global__ __launch_bounds__(256) void gemm_bf16(
    const unsigned short* __restrict__ A, const unsigned short* __restrict__ BT,
    const float* __restrict__ bias, unsigned short* __restrict__ C,
    const float* __restrict__ Wq, float* __restrict__ part, int nGemmBlocks) {
  __shared__ __align__(16) unsigned short As[2][GM * 32];   // 8 KB
  __shared__ __align__(16) unsigned short Bs[2][GN * 32];   // 16 KB
  __shared__ float gs[4][32];

  const int flat = blockIdx.x;
  const int tid  = threadIdx.x;

  if (flat >= nGemmBlocks) {
    // ---- fused q0 partial: part[(slab*4+b)*D+n] = sum_k g[b,0,k]*Wq[k,n]
    const int qb = flat - nGemmBlocks;   // 0..127
    const int slab = qb >> 2;            // 0..31
    const int n = (qb & 3) * 256 + tid;  // 0..1023
    if (tid < 128) {
      const int b = tid >> 5, kk = tid & 31;
      gs[b][kk] = bf2f(A[(size_t)b * S_ * D_ + slab * 32 + kk]);
    }
    __syncthreads();
    float a0 = 0.f, a1 = 0.f, a2 = 0.f, a3 = 0.f;
#pragma unroll
    for (int kk = 0; kk < 32; ++kk) {
      const float w = Wq[(size_t)(slab * 32 + kk) * D_ + n];
      a0 = fmaf(gs[0][kk], w, a0);
      a1 = fmaf(gs[1][kk], w, a1);
      a2 = fmaf(gs[2][kk], w, a2);
      a3 = fmaf(gs[3][kk], w, a3);
    }
    part[(size_t)(slab * 4 + 0) * D_ + n] = a0;
    part[(size_t)(slab * 4 + 1) * D_ + n] = a1;
    part[(size_t)(slab * 4 + 2) * D_ + n] = a2;
    part[(size_t)(slab * 4 + 3) * D_ + n] = a3;
    return;
  }

  // ---- GEMM path (XCD-aware decode) ----
  const int bx = flat >> 6;       // N tiles: 8
  const int by = flat & 63;       // M tiles: 64
  const int wv   = tid >> 6;
  const int lane = tid & 63;
  const int m0 = by * GM;
  const int n0 = bx * GN;

  const int colOff = (lane & 3) * 8;
  const size_t aOff  = (size_t)(m0 + 16 * wv + (lane >> 2)) * 1024 + colOff;
  const size_t bOff0 = (size_t)(n0 + 32 * wv + (lane >> 2)) * 1024 + colOff;
  const size_t bOff1 = bOff0 + (size_t)16 * 1024;

  const int l15  = lane & 15;
  const int quad = lane >> 4;

  f32x4 acc[4][2];
#pragma unroll
  for (int i = 0; i < 4; ++i)
#pragma unroll
    for (int j = 0; j < 2; ++j) acc[i][j] = (f32x4){0.f, 0.f, 0.f, 0.f};

#pragma unroll 1
  for (int k0 = 0; k0 < 1024; k0 += 64) {
    __syncthreads();                      // prior LDS reads done
#pragma unroll
    for (int ks = 0; ks < 2; ++ks) {
      gl_lds16(A  + aOff  + k0 + ks * 32, &As[ks][wv * 512]);
      gl_lds16(BT + bOff0 + k0 + ks * 32, &Bs[ks][wv * 1024]);
      gl_lds16(BT + bOff1 + k0 + ks * 32, &Bs[ks][wv * 1024 + 512]);
    }
    __syncthreads();                      // vmcnt drain: LDS writes visible

#pragma unroll
    for (int ks = 0; ks < 2; ++ks) {
      bf16x8 af[4], bfr[2];
#pragma unroll
      for (int mi = 0; mi < 4; ++mi)
        af[mi] = *(const bf16x8*)(&As[ks][(mi * 16 + l15) * 32 + quad * 8]);
#pragma unroll
      for (int ni = 0; ni < 2; ++ni)
        bfr[ni] =
            *(const bf16x8*)(&Bs[ks][(wv * 32 + ni * 16 + l15) * 32 + quad * 8]);
#pragma unroll
      for (int mi = 0; mi < 4; ++mi)
#pragma unroll
        for (int ni = 0; ni < 2; ++ni)
          acc[mi][ni] = __builtin_amdgcn_mfma_f32_16x16x32_bf16(
              af[mi], bfr[ni], acc[mi][ni], 0, 0, 0);
    }
  }

  // epilogue: C/D layout col = lane&15, row = quad*4 + r (m89/m91 verified)
#pragma unroll
  for (int ni = 0; ni < 2; ++ni) {
    const int n = n0 + wv * 32 + ni * 16 + l15;
    const float bv = bias[n];
#pragma unroll
    for (int mi = 0; mi < 4; ++mi) {
#pragma unroll
      for (int r = 0; r < 4; ++r) {
        const int m = m0 + mi * 16 + quad * 4 + r;
        C[(size_t)m * 1024 + n] = f2bf(acc[mi][ni][r] + bv);
      }
    }
  }
}

// ---------------------------------------------------------------------------
// Attention row-0 scores (round-6 verbatim).
// ---------------------------------------------------------------------------
__global__ __launch_bounds__(256) void attn_scores_kernel(
    const unsigned short* __restrict__ Kbf, const float* __restrict__ part,
    const float* __restrict__ bq, const float* __restrict__ tab,
    const int* __restrict__ mask, float* __restrict__ scores,
    float* __restrict__ mS) {
  const int bi = blockIdx.x;
  const int b = bi >> 9;
  const int h = (bi >> 5) & 15;
  const int chunk = bi & 31;
  const int tid = threadIdx.x;
  const int bh = b * H_ + h;
  const int sl = tid >> 3;  // 0..31
  const int j  = tid & 7;   // 16B chunk within the 64-elem row
  const int s  = chunk * 32 + sl;

  __shared__ float q0s[DK_];
  __shared__ float wredm[4];
  __shared__ float wreds[4];

  if (tid < 64) {
    const int n = h * DK_ + tid;
    float v = bq[n];
#pragma unroll
    for (int sl2 = 0; sl2 < 32; ++sl2)
      v += part[(size_t)(sl2 * 4 + b) * D_ + n];
    q0s[tid] = v;
  }
  __syncthreads();

  const ushort4* kp =
      (const ushort4*)(Kbf + ((size_t)(b * S_ + s)) * D_ + h * DK_ + j * 8);
  const ushort4 k0 = kp[0], k1 = kp[1];
  const float4* tb = (const float4*)(tab + (size_t)s * 64 + j * 8);
  const float4 t0 = tb[0], t1 = tb[1];

  float dot = 0.f;
  {
    const float ka = bf2f(k0.x), kb = bf2f(k0.y);
    dot += q0s[j * 8 + 0] * (ka * t0.x - kb * t0.y) +
           q0s[j * 8 + 1] * (kb * t0.x + ka * t0.y);
  }
  {
    const float ka = bf2f(k0.z), kb = bf2f(k0.w);
    dot += q0s[j * 8 + 2] * (ka * t0.z - kb * t0.w) +
           q0s[j * 8 + 3] * (kb * t0.z + ka * t0.w);
  }
  {
    const float ka = bf2f(k1.x), kb = bf2f(k1.y);
    dot += q0s[j * 8 + 4] * (ka * t1.x - kb * t1.y) +
           q0s[j * 8 + 5] * (kb * t1.x + ka * t1.y);
  }
  {
    const float ka = bf2f(k1.z), kb = bf2f(k1.w);
    dot += q0s[j * 8 + 6] * (ka * t1.z - kb * t1.w) +
           q0s[j * 8 + 7] * (kb * t1.z + ka * t1.w);
  }
  dot += __shfl_xor(dot, 1);
  dot += __shfl_xor(dot, 2);
  dot += __shfl_xor(dot, 4);
  dot *= 0.125f;  // 1/sqrt(64)
  if (mask[b * S_ + s] == 0) dot = -1e9f;
  if (j == 0) scores[(size_t)bh * S_ + s] = dot;

  float mx = dot;
#pragma unroll
  for (int off = 8; off < 64; off <<= 1) mx = fmaxf(mx, __shfl_xor(mx, off));
  if ((tid & 63) == 0) wredm[tid >> 6] = mx;
  __syncthreads();
  mx = fmaxf(fmaxf(wredm[0], wredm[1]), fmaxf(wredm[2], wredm[3]));

  float e = (j == 0) ? expf(dot - mx) : 0.f;
#pragma unroll
  for (int off = 1; off < 64; off <<= 1) e += __shfl_xor(e, off);
  if ((tid & 63) == 0) wreds[tid >> 6] = e;
  __syncthreads();
  if (tid == 0) {
    mS[(size_t)(bh * 32 + chunk) * 2 + 0] = mx;
    mS[(size_t)(bh * 32 + chunk) * 2 + 1] =
        wreds[0] + wreds[1] + wreds[2] + wreds[3];
  }
}

// ---------------------------------------------------------------------------
// Conv1d (16->1024, k=3, pad=1) + bias + ReLU — ROUND-12 REWRITE (v3).
// v2 (round 11) was still LDS-issue-bound: 48 broadcast ds_reads per o-iter,
// FMA:LDS = 1:1. v3 tiles BOTH output dims per thread (8o x 8s register
// tile, GEMM-style): per c, 3 b128 (p window) + 6 b128 (weights, staged
// TRANSPOSED [ct][o] for vector reads) feed 192 FMA -> FMA:LDS = 21:1.
// Per wave: 144 b128 + 3072 FMA -> VALU-bound ~2.6us issue; 512B-contiguous
// stores per (ty,i) group. Block = (b, o-tile 128, s-tile 128); grid
// (8,4,8)=256 = 1/CU. Same (c-major, t-minor, bias-first) summation order ->
// bitwise-same output as rounds 10/11.
// ---------------------------------------------------------------------------
__global__ __launch_bounds__(256) void conv_norm_relu_kernel(
    const float* __restrict__ scores, const float* __restrict__ mS,
    const float* __restrict__ cw, const float* __restrict__ cb,
    float* __restrict__ out) {
  const int b  = blockIdx.y;
  const int s0 = blockIdx.x * 128;
  const int o0 = blockIdx.z * 128;
  const int tid = threadIdx.x;
  const int tx = tid & 15;   // s group: s = s0 + tx*8 + j
  const int ty = tid >> 4;   // o group: o = o0 + ty*8 + i

  __shared__ float msh[16], ish[16];
  __shared__ __align__(16) float wT[48][128];  // transposed weights, 24 KB
  __shared__ float cbs[128];
  __shared__ __align__(16) float pm[16][132];  // p, row stride 132 (16B-align)

  // softmax combine (round-6 proven)
  if (tid < 16) {
    const int bh = b * H_ + tid;
    float m = -3e38f;
#pragma unroll
    for (int c = 0; c < 32; ++c)
      m = fmaxf(m, mS[(size_t)(bh * 32 + c) * 2]);
    float S = 0.f;
#pragma unroll
    for (int c = 0; c < 32; ++c)
      S += mS[(size_t)(bh * 32 + c) * 2 + 1] *
           expf(mS[(size_t)(bh * 32 + c) * 2] - m);
    msh[tid] = m;
    ish[tid] = 1.f / S;
  }
  // weight tile, transposed: wT[ct][ol] = cw[(o0+ol)*48 + ct]
  // (global reads coalesced; LDS scatter is a one-time ~400-cycle cost)
  for (int i = tid; i < 128 * 48; i += 256) {
    const int ol = i / 48, ct = i % 48;
    wT[ct][ol] = cw[(size_t)(o0 + ol) * 48 + ct];
  }
  if (tid < 128) cbs[tid] = cb[o0 + tid];
  __syncthreads();  // msh/ish ready

  // p halo: pm[c][ss] = p(b, c, s0-1+ss), ss in [0,130)
  for (int i = tid; i < 16 * 130; i += 256) {
    const int c = i / 130, ss = i % 130;
    const int gs = s0 - 1 + ss;
    pm[c][ss] = (gs >= 0 && gs < S_)
                    ? expf(scores[(size_t)(b * H_ + c) * S_ + gs] - msh[c]) *
                          ish[c]
                    : 0.f;
  }
  __syncthreads();

  float acc[8][8];
#pragma unroll
  for (int i = 0; i < 8; ++i) {
    const float cv = cbs[ty * 8 + i];
#pragma unroll
    for (int j = 0; j < 8; ++j) acc[i][j] = cv;
  }

#pragma unroll
  for (int c = 0; c < 16; ++c) {
    float p[12];
    *(float4*)(p + 0) = *(const float4*)&pm[c][tx * 8 + 0];
    *(float4*)(p + 4) = *(const float4*)&pm[c][tx * 8 + 4];
    *(float4*)(p + 8) = *(const float4*)&pm[c][tx * 8 + 8];
#pragma unroll
    for (int t = 0; t < 3; ++t) {
      float w[8];
      *(float4*)(w + 0) = *(const float4*)&wT[c * 3 + t][ty * 8 + 0];
      *(float4*)(w + 4) = *(const float4*)&wT[c * 3 + t][ty * 8 + 4];
#pragma unroll
      for (int i = 0; i < 8; ++i)
#pragma unroll
        for (int j = 0; j < 8; ++j)
          acc[i][j] = fmaf(p[j + t], w[i], acc[i][j]);
    }
  }

#pragma unroll
  for (int i = 0; i < 8; ++i) {
    float* orow =
        out + ((size_t)b * D_ + o0 + ty * 8 + i) * S_ + s0 + tx * 8;
    float4 v0, v1;
    v0.x = fmaxf(acc[i][0], 0.f); v0.y = fmaxf(acc[i][1], 0.f);
    v0.z = fmaxf(acc[i][2], 0.f); v0.w = fmaxf(acc[i][3], 0.f);
    v1.x = fmaxf(acc[i][4], 0.f); v1.y = fmaxf(acc[i][5], 0.f);
    v1.z = fmaxf(acc[i][6], 0.f); v1.w = fmaxf(acc[i][7], 0.f);
    *(float4*)(orow + 0) = v0;
    *(float4*)(orow + 4) = v1;
  }
}

// ---------------------------------------------------------------------------
// Workspace (round-6 layout, peak ~29.1 MB):
//  [ 0, 8M) Xbf | [8,16M) G | [16,24M) Kbf | [24,26M) WGT | [26,28M) WkT
//  [28M,+512K) part | +256K ropeT | +256K scores | +16K mS
// ---------------------------------------------------------------------------
extern "C" void kernel_launch(void* const* d_in, const int* in_sizes, int n_in,
                              void* d_out, int out_size, void* d_ws,
                              size_t ws_size, hipStream_t stream) {
  const float* x    = (const float*)d_in[0];
  const int*   mask = (const int*)d_in[1];
  const float* W_G  = (const float*)d_in[2];
  const float* b_G  = (const float*)d_in[3];
  const float* Wq   = (const float*)d_in[4];
  const float* bq   = (const float*)d_in[5];
  const float* Wk   = (const float*)d_in[6];
  const float* bk   = (const float*)d_in[7];
  const float* cw   = (const float*)d_in[8];
  const float* cb   = (const float*)d_in[9];
  float* out = (float*)d_out;

  char* ws = (char*)d_ws;
  unsigned short* Xbf = (unsigned short*)(ws);
  unsigned short* G   = (unsigned short*)(ws + (8u << 20));
  unsigned short* Kbf = (unsigned short*)(ws + (16u << 20));
  unsigned short* WGT = (unsigned short*)(ws + (24u << 20));
  unsigned short* WkT = (unsigned short*)(ws + (26u << 20));
  float* part   = (float*)(ws + (28u << 20));
  float* ropeT  = (float*)(ws + (28u << 20) + (512u << 10));
  float* scores = (float*)(ws + (28u << 20) + (768u << 10));
  float* mS     = (float*)(ws + (28u << 20) + (1024u << 10));

  prep_kernel<<<4224, 256, 0, stream>>>(x, W_G, Wk, Xbf, WGT, WkT, ropeT);
  gemm_bf16<<<512, 256, 0, stream>>>(Xbf, WGT, b_G, G, nullptr, nullptr, 512);
  gemm_bf16<<<640, 256, 0, stream>>>(G, WkT, bk, Kbf, Wq, part, 512);
  attn_scores_kernel<<<2048, 256, 0, stream>>>(Kbf, part, bq, ropeT, mask,
                                               scores, mS);
  conv_norm_relu_kernel<<<dim3(8, B_, 8), 256, 0, stream>>>(
      scores, mS, cw, cb, out);
}